// Round 19
// baseline (160.185 us; speedup 1.0000x reference)
//
#include <hip/hip_runtime.h>
#include <math.h>

#define BN_EPS 1e-5f
#define EB_CHUNK 4096

typedef _Float16 f16x8 __attribute__((ext_vector_type(8)));
typedef float f32x4 __attribute__((ext_vector_type(4)));

__device__ __forceinline__ float gelu_fast(float x) {
    float z  = x * 0.7071067811865475f;
    float az = fabsf(z);
    float t  = __builtin_amdgcn_rcpf(1.0f + 0.3275911f * az);
    float poly = t * (0.254829592f + t * (-0.284496736f + t * (1.421413741f +
                 t * (-1.453152027f + t * 1.061405429f))));
    float e = __expf(-z * z);
    float erfv = copysignf(1.0f - poly * e, z);
    return 0.5f * x * (1.0f + erfv);
}

// ---------------- fat prep: BN-fold 6 layers (fragment-linear) + out_W prep
// + bin_count, one launch ---------------------------------------------------
struct PrepSet {
    const float *g, *b, *m, *v, *W, *bias;
    _Float16* WT;
    float* bout;
    int K;
};
struct PrepAll { PrepSet s[6]; };

__global__ __launch_bounds__(256) void prep_fat(
    PrepAll P,
    const float* __restrict__ outW, const float* __restrict__ outB,
    _Float16* __restrict__ WTc, float* __restrict__ pbC,
    const int* __restrict__ esrc, int* __restrict__ hist, int E, int NWG)
{
    __shared__ float red[256];
    const int b = blockIdx.x;
    const int t = threadIdx.x;

    if (b < 768) {                       // ---- BN-folded layer weights ----
        const int layer = b >> 7;
        const int j = b & 127;
        const PrepSet S = P.s[layer];
        const int NKK = S.K >> 5;
        const int colblk = j >> 5;
        const int n   = (j >> 4) & 1;
        const int lrow = j & 15;
        float acc = 0.0f;
        for (int k = t; k < S.K; k += 256) {
            float rs = rsqrtf(S.v[k] + BN_EPS) * S.g[k];
            float w  = S.W[(size_t)k * 128 + j];
            int kk     = k >> 5;
            int lanehi = (k >> 3) & 3;
            int elem   = k & 7;
            int lane   = lanehi * 16 + lrow;
            size_t idx = ((size_t)((colblk * NKK + kk) * 2 + n) * 64 + lane) * 8 + elem;
            S.WT[idx] = (_Float16)(rs * w);
            acc += (S.b[k] - S.m[k] * rs) * w;
        }
        red[t] = acc;
        __syncthreads();
        #pragma unroll
        for (int s = 128; s > 0; s >>= 1) {
            if (t < s) red[t] += red[t + s];
            __syncthreads();
        }
        if (t == 0) S.bout[j] = S.bias[j] + red[0];
        return;
    }

    if (b < 800) {                       // ---- out_W fragment-linear ----
        const int j = b - 768;           // 0..31
        if (t < 128) {
            int k = t;
            float w = outW[(size_t)k * 32 + j];
            int kk     = k >> 5;
            int lanehi = (k >> 3) & 3;
            int elem   = k & 7;
            int lane   = lanehi * 16 + (j & 15);
            int n      = (j >> 4) & 1;
            size_t idx = ((size_t)(kk * 2 + n) * 64 + lane) * 8 + elem;
            WTc[idx] = (_Float16)w;
        }
        if (t == 0) pbC[j] = outB[j];
        return;
    }

    // ---- bin_count ----
    const int wg = b - 800;
    int* lh = (int*)red;
    lh[t] = 0;
    __syncthreads();
    const int lo = wg * EB_CHUNK;
    const int hi = min(lo + EB_CHUNK, E);
    for (int e = lo + t; e < hi; e += 256)
        atomicAdd(&lh[esrc[e] >> 8], 1);
    __syncthreads();
    hist[t * NWG + wg] = lh[t];
}

// ---------------- fused double FFN (+optional scatter blocks, +fused final C)
// FULL W-fragment preload: all 24 frags loaded before the stage barrier and
// pinned live via asm; the barrier's vmcnt(0) drain completes them for free.
template<typename TIn, bool HAS_OUT1, bool DO_SCATTER, bool FUSE_C>
__global__ __launch_bounds__(256) void ffn2_mfma(
    const TIn* __restrict__ x1, int K1,
    const _Float16* __restrict__ x2,
    const _Float16* __restrict__ WTa, const float* __restrict__ biasa,
    const _Float16* __restrict__ WTb, const float* __restrict__ biasb,
    _Float16* __restrict__ out1,
    _Float16* __restrict__ out2, int N,
    const int* __restrict__ esrc, const int* __restrict__ edst,
    const int* __restrict__ hist, const int* __restrict__ rowsum,
    unsigned int* __restrict__ bucketed, int E, int NWG,
    const _Float16* __restrict__ WTc, const float* __restrict__ pbC,
    float* __restrict__ outC)
{
    constexpr int K   = 256;
    constexpr int KB  = 512;
    constexpr int CPR = 32;
    constexpr int NKA = 8;
    constexpr int KB2 = 256;
    constexpr int NKB = 4;
    __shared__ __align__(16) char xs[64 * KB];

    const int tid  = threadIdx.x;

    if constexpr (DO_SCATTER) {          // extra blocks: bin_scatter
        const int nffn = (N + 63) >> 6;
        if ((int)blockIdx.x >= nffn) {
            const int wg = blockIdx.x - nffn;
            int* sh  = (int*)xs;          // 256 scan
            int* cur = sh + 256;
            int v = rowsum[tid];
            sh[tid] = v;
            __syncthreads();
            #pragma unroll
            for (int off = 1; off < 256; off <<= 1) {
                int x = (tid >= off) ? sh[tid - off] : 0;
                __syncthreads();
                sh[tid] += x;
                __syncthreads();
            }
            cur[tid] = hist[tid * NWG + wg] + (sh[tid] - v);  // + bbase[tid]
            __syncthreads();
            const int lo = wg * EB_CHUNK;
            const int hi = min(lo + EB_CHUNK, E);
            for (int e = lo + tid; e < hi; e += 256) {
                int s = esrc[e];
                int pos = atomicAdd(&cur[s >> 8], 1);
                bucketed[pos] = ((unsigned)s << 16) | (unsigned)edst[e];
            }
            return;
        }
    }

    const int row0 = blockIdx.x * 64;
    const int wave = tid >> 6;
    const int lane = tid & 63;
    const int lrow = lane & 15;
    const int lj   = lane >> 4;
    const int lk   = lj * 8;
    const int colbase = wave * 32;

    const _Float16* wfA = WTa + (size_t)wave * NKA * 2 * 512 + lane * 8;
    const _Float16* wfB = WTb + (size_t)wave * NKB * 2 * 512 + lane * 8;

    // ---- issue ALL W-fragment loads up front (24 x 16B, dense) ----
    f16x8 fA[NKA][2];
    #pragma unroll
    for (int kk = 0; kk < NKA; ++kk) {
        fA[kk][0] = *reinterpret_cast<const f16x8*>(wfA + (kk * 2 + 0) * 512);
        fA[kk][1] = *reinterpret_cast<const f16x8*>(wfA + (kk * 2 + 1) * 512);
    }
    f16x8 fB[NKB][2];
    #pragma unroll
    for (int kk = 0; kk < NKB; ++kk) {
        fB[kk][0] = *reinterpret_cast<const f16x8*>(wfB + (kk * 2 + 0) * 512);
        fB[kk][1] = *reinterpret_cast<const f16x8*>(wfB + (kk * 2 + 1) * 512);
    }

    // ---- stage 64 x 256 fp16 into LDS (swizzled slot = chunk ^ (r&7)) ----
    bool gload = false;
    if constexpr (sizeof(TIn) == 2) {
        if (row0 + 64 <= N) {
            gload = true;
            #pragma unroll
            for (int i = 0; i < 8; ++i) {
                int r  = (wave << 4) + i * 2 + (lane >> 5);
                int j  = lane & 31;
                int cs = j ^ (r & 7);
                const _Float16* g = (cs * 8 < K1)
                    ? (const _Float16*)x1 + (size_t)(row0 + r) * K1 + cs * 8
                    : x2 + (size_t)(row0 + r) * (K - K1) + (cs * 8 - K1);
                char* ldsbase = &xs[(wave << 13) + i * 1024];
                __builtin_amdgcn_global_load_lds(
                    (const __attribute__((address_space(1))) void*)g,
                    (__attribute__((address_space(3))) void*)ldsbase,
                    16, 0, 0);
            }
        }
    }
    if (!gload) {
        for (int c = tid; c < 64 * CPR; c += 256) {
            int r  = c / CPR;
            int kc = c % CPR;
            int k0 = kc * 8;
            int row = row0 + r;
            f16x8 h;
            #pragma unroll
            for (int i = 0; i < 8; ++i) h[i] = (_Float16)0.0f;
            if (row < N) {
                if (k0 < K1) {
                    const TIn* p = x1 + (size_t)row * K1 + k0;
                    if constexpr (sizeof(TIn) == 2) {
                        h = *reinterpret_cast<const f16x8*>(p);
                    } else {
                        const float4 a = *reinterpret_cast<const float4*>(p);
                        const float4 b = *reinterpret_cast<const float4*>(p + 4);
                        h[0]=(_Float16)a.x; h[1]=(_Float16)a.y; h[2]=(_Float16)a.z; h[3]=(_Float16)a.w;
                        h[4]=(_Float16)b.x; h[5]=(_Float16)b.y; h[6]=(_Float16)b.z; h[7]=(_Float16)b.w;
                    }
                } else {
                    h = *reinterpret_cast<const f16x8*>(
                        x2 + (size_t)row * (K - K1) + (k0 - K1));
                }
            }
            int byte = r * KB + ((k0 * 2) ^ ((r & 7) << 4));
            *reinterpret_cast<f16x8*>(&xs[byte]) = h;
        }
    }

    // pin all fragments live BEFORE the barrier: their loads complete in the
    // same vmcnt(0) drain the barrier performs for global_load_lds.
    asm volatile("" ::
        "v"(fA[0][0]), "v"(fA[0][1]), "v"(fA[1][0]), "v"(fA[1][1]),
        "v"(fA[2][0]), "v"(fA[2][1]), "v"(fA[3][0]), "v"(fA[3][1]),
        "v"(fA[4][0]), "v"(fA[4][1]), "v"(fA[5][0]), "v"(fA[5][1]));
    asm volatile("" ::
        "v"(fA[6][0]), "v"(fA[6][1]), "v"(fA[7][0]), "v"(fA[7][1]),
        "v"(fB[0][0]), "v"(fB[0][1]), "v"(fB[1][0]), "v"(fB[1][1]),
        "v"(fB[2][0]), "v"(fB[2][1]), "v"(fB[3][0]), "v"(fB[3][1]));

    __syncthreads();

    f32x4 acc[4][2];
    #pragma unroll
    for (int m = 0; m < 4; ++m) {
        acc[m][0] = (f32x4){0.f,0.f,0.f,0.f};
        acc[m][1] = (f32x4){0.f,0.f,0.f,0.f};
    }

    // ---- layer A: pure LDS-read + MFMA (no global loads) ----
    #pragma unroll
    for (int kk = 0; kk < NKA; ++kk) {
        #pragma unroll
        for (int m = 0; m < 4; ++m) {
            int r  = m * 16 + lrow;
            int k0 = kk * 32 + lk;
            f16x8 a = *reinterpret_cast<const f16x8*>(
                &xs[r * KB + ((k0 * 2) ^ ((lrow & 7) << 4))]);
            acc[m][0] = __builtin_amdgcn_mfma_f32_16x16x32_f16(a, fA[kk][0], acc[m][0], 0, 0, 0);
            acc[m][1] = __builtin_amdgcn_mfma_f32_16x16x32_f16(a, fA[kk][1], acc[m][1], 0, 0, 0);
        }
    }

    // epilogue A: activation -> (optional) global + mid-LDS (layer-B layout)
    const float ba0 = biasa[colbase + lrow];
    const float ba1 = biasa[colbase + 16 + lrow];
    __syncthreads();   // all layer-A ds_reads complete before overwriting xs
    #pragma unroll
    for (int m = 0; m < 4; ++m) {
        #pragma unroll
        for (int j = 0; j < 4; ++j) {
            int lrowq = m * 16 + lj * 4 + j;
            float v0 = gelu_fast(acc[m][0][j] + ba0);
            float v1 = gelu_fast(acc[m][1][j] + ba1);
            if constexpr (HAS_OUT1) {
                if (row0 + lrowq < N) {
                    _Float16* o = out1 + (size_t)(row0 + lrowq) * 128 + colbase + lrow;
                    o[0]  = (_Float16)v0;
                    o[16] = (_Float16)v1;
                }
            }
            int c0 = (colbase + lrow) * 2;
            int c1 = (colbase + 16 + lrow) * 2;
            int swz = (lrowq & 7) << 4;
            *reinterpret_cast<_Float16*>(&xs[lrowq * KB2 + (c0 ^ swz)]) = (_Float16)v0;
            *reinterpret_cast<_Float16*>(&xs[lrowq * KB2 + (c1 ^ swz)]) = (_Float16)v1;
        }
    }
    __syncthreads();

    #pragma unroll
    for (int m = 0; m < 4; ++m) {
        acc[m][0] = (f32x4){0.f,0.f,0.f,0.f};
        acc[m][1] = (f32x4){0.f,0.f,0.f,0.f};
    }

    // ---- layer B: pure LDS-read + MFMA ----
    #pragma unroll
    for (int kk = 0; kk < NKB; ++kk) {
        #pragma unroll
        for (int m = 0; m < 4; ++m) {
            int r  = m * 16 + lrow;
            int k0 = kk * 32 + lk;
            f16x8 a = *reinterpret_cast<const f16x8*>(
                &xs[r * KB2 + ((k0 * 2) ^ ((lrow & 7) << 4))]);
            acc[m][0] = __builtin_amdgcn_mfma_f32_16x16x32_f16(a, fB[kk][0], acc[m][0], 0, 0, 0);
            acc[m][1] = __builtin_amdgcn_mfma_f32_16x16x32_f16(a, fB[kk][1], acc[m][1], 0, 0, 0);
        }
    }

    const float bb0 = biasb[colbase + lrow];
    const float bb1 = biasb[colbase + 16 + lrow];

    if constexpr (!FUSE_C) {
        // epilogue B: gelu -> global fp16 (direct register stores)
        #pragma unroll
        for (int m = 0; m < 4; ++m) {
            #pragma unroll
            for (int j = 0; j < 4; ++j) {
                int grow = row0 + m * 16 + lj * 4 + j;
                if (grow >= N) continue;
                _Float16* o = out2 + (size_t)grow * 128 + colbase + lrow;
                o[0]  = (_Float16)gelu_fast(acc[m][0][j] + bb0);
                o[16] = (_Float16)gelu_fast(acc[m][1][j] + bb1);
            }
        }
    } else {
        // epilogue B: gelu -> LDS (layer-C input), then fused final linear
        __syncthreads();
        #pragma unroll
        for (int m = 0; m < 4; ++m) {
            #pragma unroll
            for (int j = 0; j < 4; ++j) {
                int lrowq = m * 16 + lj * 4 + j;
                float v0 = gelu_fast(acc[m][0][j] + bb0);
                float v1 = gelu_fast(acc[m][1][j] + bb1);
                int c0 = (colbase + lrow) * 2;
                int c1 = (colbase + 16 + lrow) * 2;
                int swz = (lrowq & 7) << 4;
                *reinterpret_cast<_Float16*>(&xs[lrowq * KB2 + (c0 ^ swz)]) = (_Float16)v0;
                *reinterpret_cast<_Float16*>(&xs[lrowq * KB2 + (c1 ^ swz)]) = (_Float16)v1;
            }
        }
        __syncthreads();

        // layer C: each wave owns rows [wave*16, wave*16+16), 32 cols
        const _Float16* wfC = WTc + lane * 8;
        f32x4 accC[2];
        accC[0] = (f32x4){0.f,0.f,0.f,0.f};
        accC[1] = (f32x4){0.f,0.f,0.f,0.f};
        #pragma unroll
        for (int kk = 0; kk < 4; ++kk) {
            int r  = wave * 16 + lrow;
            int k0 = kk * 32 + lk;
            f16x8 a = *reinterpret_cast<const f16x8*>(
                &xs[r * KB2 + ((k0 * 2) ^ ((lrow & 7) << 4))]);
            f16x8 c0 = *reinterpret_cast<const f16x8*>(wfC + (kk * 2 + 0) * 512);
            f16x8 c1 = *reinterpret_cast<const f16x8*>(wfC + (kk * 2 + 1) * 512);
            accC[0] = __builtin_amdgcn_mfma_f32_16x16x32_f16(a, c0, accC[0], 0, 0, 0);
            accC[1] = __builtin_amdgcn_mfma_f32_16x16x32_f16(a, c1, accC[1], 0, 0, 0);
        }
        const float bc0 = pbC[lrow];
        const float bc1 = pbC[16 + lrow];
        #pragma unroll
        for (int j = 0; j < 4; ++j) {
            int grow = row0 + wave * 16 + lj * 4 + j;
            if (grow >= N) continue;
            float* o = outC + (size_t)grow * 32 + lrow;
            o[0]  = accC[0][j] + bc0;
            o[16] = accC[1][j] + bc1;
        }
    }
}

// ---------------- CSR: per-bin chunk scan (hist cursors + rowsum) -----------
__global__ __launch_bounds__(256) void bin_row_scan(
    int* __restrict__ hist, int* __restrict__ rowsum, int NWG)
{
    __shared__ int sh[256];
    const int t = threadIdx.x;
    const int b = blockIdx.x;
    int v = (t < NWG) ? hist[b * NWG + t] : 0;
    sh[t] = v;
    __syncthreads();
    #pragma unroll
    for (int off = 1; off < 256; off <<= 1) {
        int x = (t >= off) ? sh[t - off] : 0;
        __syncthreads();
        sh[t] += x;
        __syncthreads();
    }
    if (t < NWG) hist[b * NWG + t] = sh[t] - v;
    if (t == 255) rowsum[b] = sh[255];
}

// per bucket: recompute bbase locally from rowsum (no serial bbase_scan)
__global__ __launch_bounds__(256) void bucket_csr(
    const unsigned int* __restrict__ bucketed, const int* __restrict__ rowsum,
    int* __restrict__ offs, int* __restrict__ csr_dst, int N)
{
    __shared__ int sh[256];
    __shared__ int exc[256];
    __shared__ int cnt[256];
    __shared__ int sc[256];
    __shared__ int cur[256];
    const int t = threadIdx.x;
    const int b = blockIdx.x;

    int v = rowsum[t];
    sh[t] = v;
    __syncthreads();
    #pragma unroll
    for (int off = 1; off < 256; off <<= 1) {
        int x = (t >= off) ? sh[t - off] : 0;
        __syncthreads();
        sh[t] += x;
        __syncthreads();
    }
    exc[t] = sh[t] - v;
    __syncthreads();
    const int base = exc[b];
    const int bsz  = rowsum[b];

    cnt[t] = 0;
    __syncthreads();
    for (int i = t; i < bsz; i += 256) {
        unsigned key = bucketed[base + i];
        atomicAdd(&cnt[(key >> 16) & 255], 1);
    }
    __syncthreads();
    int c = cnt[t];
    sc[t] = c;
    __syncthreads();
    #pragma unroll
    for (int off = 1; off < 256; off <<= 1) {
        int x = (t >= off) ? sc[t - off] : 0;
        __syncthreads();
        sc[t] += x;
        __syncthreads();
    }
    int myoff = sc[t] - c;
    cur[t] = myoff;
    int node = b * 256 + t;
    if (node <= N) offs[node] = base + myoff;
    __syncthreads();
    for (int i = t; i < bsz; i += 256) {
        unsigned key = bucketed[base + i];
        int sl = (key >> 16) & 255;
        int pos = base + atomicAdd(&cur[sl], 1);
        csr_dst[pos] = (int)(key & 0xFFFFu);
    }
}

// one wave per node, 4 neighbors per load step (16 lanes x 16B each = 1 row).
__global__ __launch_bounds__(256) void aggregate_kernel(
    const _Float16* __restrict__ y,
    const int* __restrict__ csr_dst, const int* __restrict__ offs,
    _Float16* __restrict__ agg, int N)
{
    const int wave = (blockIdx.x * blockDim.x + threadIdx.x) >> 6;
    const int lane = threadIdx.x & 63;
    if (wave >= N) return;
    const int lo = offs[wave];
    const int hi = offs[wave + 1];
    const int sub = lane >> 4;
    const int col = (lane & 15) * 8;

    float a[8];
    #pragma unroll
    for (int j = 0; j < 8; ++j) a[j] = 0.0f;

    for (int base = lo; base < hi; base += 64) {
        int myd = (base + lane < hi) ? csr_dst[base + lane] : -1;
        int m = hi - base;
        if (m > 64) m = 64;
        int ng = (m + 3) >> 2;
        #pragma unroll 8
        for (int i = 0; i < ng; ++i) {
            int d = __shfl(myd, i * 4 + sub);
            if (d >= 0) {
                f16x8 v = *reinterpret_cast<const f16x8*>(
                    y + (size_t)d * 128 + col);
                #pragma unroll
                for (int j = 0; j < 8; ++j) a[j] += (float)v[j];
            }
        }
    }

    #pragma unroll
    for (int j = 0; j < 8; ++j) {
        a[j] += __shfl_xor(a[j], 16);
        a[j] += __shfl_xor(a[j], 32);
    }

    if (lane < 16) {
        const float inv = (hi > lo) ? 1.0f / (float)(hi - lo) : 0.0f;
        f16x8 o;
        #pragma unroll
        for (int j = 0; j < 8; ++j) o[j] = (_Float16)(a[j] * inv);
        *reinterpret_cast<f16x8*>(agg + (size_t)wave * 128 + col) = o;
    }
}

extern "C" void kernel_launch(void* const* d_in, const int* in_sizes, int n_in,
                              void* d_out, int out_size, void* d_ws, size_t ws_size,
                              hipStream_t stream) {
    const float* nf   = (const float*)d_in[0];
    const int*   esrc = (const int*)d_in[1];
    const int*   edst = (const int*)d_in[2];
    auto in = [&](int i) { return (const float*)d_in[i]; };

    const int N = in_sizes[3];       // 50000
    const int E = in_sizes[1];       // 800000
    const int H = 128;

    _Float16* xA  = (_Float16*)d_ws;
    _Float16* xB  = xA + (size_t)N * H;
    _Float16* y   = xB + (size_t)N * H;
    _Float16* agg = y  + (size_t)N * H;

    _Float16* WT0 = agg + (size_t)N * H;                // pre   256x128
    _Float16* WT2 = WT0 + 256 * 128;                    // c1u   256x128
    _Float16* WT4 = WT2 + 256 * 128;                    // c2u   256x128
    _Float16* WT1 = WT4 + 256 * 128;                    // c1p   128x128
    _Float16* WT3 = WT1 + 128 * 128;                    // c2p   128x128
    _Float16* WT5 = WT3 + 128 * 128;                    // post  128x128
    _Float16* WTc = WT5 + 128 * 128;                    // out   128x32 frag-linear
    float* pb     = (float*)(WTc + 4096);               // 6 x 128 biases
    float* pbC    = pb + 6 * 128;                       // 32

    const int NWG = (E + EB_CHUNK - 1) / EB_CHUNK;      // 196
    const int NB  = (N + 255) >> 8;                     // 196 buckets

    int* hist      = (int*)(pbC + 32);                  // 256 * NWG
    int* rowsum    = hist + 256 * NWG;                  // 256
    int* offs      = rowsum + 256;                      // N+1
    int* csr_dst   = offs + (N + 1);                    // E
    unsigned int* bucketed = (unsigned int*)(csr_dst + E);  // E

    const int ffnGrid = (N + 63) / 64;

    // ---- weight prep + out_W prep + bin_count, one launch ----
    PrepAll P;
    const float* base[6][6] = {
        { in(4),  in(5),  in(6),  in(7),  in(8),  in(9)  },   // pre  K=256
        { in(10), in(11), in(12), in(13), in(14), in(15) },   // c1p  K=128
        { in(16), in(17), in(18), in(19), in(20), in(21) },   // c1u  K=256
        { in(22), in(23), in(24), in(25), in(26), in(27) },   // c2p  K=128
        { in(28), in(29), in(30), in(31), in(32), in(33) },   // c2u  K=256
        { in(34), in(35), in(36), in(37), in(38), in(39) },   // post K=128
    };
    _Float16* wt[6] = { WT0, WT1, WT2, WT3, WT4, WT5 };
    const int  kk[6] = { 256, 128, 256, 128, 256, 128 };
    for (int l = 0; l < 6; ++l) {
        P.s[l].g = base[l][0]; P.s[l].b = base[l][1]; P.s[l].m = base[l][2];
        P.s[l].v = base[l][3]; P.s[l].W = base[l][4]; P.s[l].bias = base[l][5];
        P.s[l].WT = wt[l]; P.s[l].bout = pb + l * 128; P.s[l].K = kk[l];
    }
    prep_fat<<<800 + NWG, 256, 0, stream>>>(
        P, in(40), in(41), WTc, pbC, esrc, hist, E, NWG);

    bin_row_scan<<<256, 256, 0, stream>>>(hist, rowsum, NWG);

    // ---- F1: pre + c1p (nf f32 -> xA, y)  ||  bin_scatter (extra blocks) ----
    ffn2_mfma<float, true, true, false><<<ffnGrid + NWG, 256, 0, stream>>>(
        nf, 256, nullptr, WT0, pb + 0*128, WT1, pb + 1*128, xA, y, N,
        esrc, edst, hist, rowsum, bucketed, E, NWG, nullptr, nullptr, nullptr);

    bucket_csr<<<NB, 256, 0, stream>>>(bucketed, rowsum, offs, csr_dst, N);

    // ---- conv1 aggregate ----
    aggregate_kernel<<<(N * 64 + 255) / 256, 256, 0, stream>>>(y, csr_dst, offs, agg, N);

    // ---- F2: c1u + c2p ([xA,agg] -> xB, y) ----
    ffn2_mfma<_Float16, true, false, false><<<ffnGrid, 256, 0, stream>>>(
        xA, 128, agg, WT2, pb + 2*128, WT3, pb + 3*128, xB, y, N,
        nullptr, nullptr, nullptr, nullptr, nullptr, 0, 0, nullptr, nullptr, nullptr);

    // ---- conv2 aggregate ----
    aggregate_kernel<<<(N * 64 + 255) / 256, 256, 0, stream>>>(y, csr_dst, offs, agg, N);

    // ---- F3: c2u + post + fused final linear -> d_out (fp32) ----
    ffn2_mfma<_Float16, false, false, true><<<ffnGrid, 256, 0, stream>>>(
        xB, 128, agg, WT4, pb + 4*128, WT5, pb + 5*128, nullptr, nullptr, N,
        nullptr, nullptr, nullptr, nullptr, nullptr, 0, 0, WTc, pbC, (float*)d_out);
}

// Round 20
// 156.601 us; speedup vs baseline: 1.0229x; 1.0229x over previous
//
#include <hip/hip_runtime.h>
#include <math.h>

#define BN_EPS 1e-5f
#define EB_CHUNK 4096

typedef _Float16 f16x8 __attribute__((ext_vector_type(8)));
typedef float f32x4 __attribute__((ext_vector_type(4)));

__device__ __forceinline__ float gelu_fast(float x) {
    float z  = x * 0.7071067811865475f;
    float az = fabsf(z);
    float t  = __builtin_amdgcn_rcpf(1.0f + 0.3275911f * az);
    float poly = t * (0.254829592f + t * (-0.284496736f + t * (1.421413741f +
                 t * (-1.453152027f + t * 1.061405429f))));
    float e = __expf(-z * z);
    float erfv = copysignf(1.0f - poly * e, z);
    return 0.5f * x * (1.0f + erfv);
}

// ---------------- fat prep: BN-fold 6 layers (fragment-linear) + out_W prep
// + bin_count, one launch ---------------------------------------------------
struct PrepSet {
    const float *g, *b, *m, *v, *W, *bias;
    _Float16* WT;
    float* bout;
    int K;
};
struct PrepAll { PrepSet s[6]; };

__global__ __launch_bounds__(256) void prep_fat(
    PrepAll P,
    const float* __restrict__ outW, const float* __restrict__ outB,
    _Float16* __restrict__ WTc, float* __restrict__ pbC,
    const int* __restrict__ esrc, int* __restrict__ hist, int E, int NWG)
{
    __shared__ float red[256];
    const int b = blockIdx.x;
    const int t = threadIdx.x;

    if (b < 768) {                       // ---- BN-folded layer weights ----
        const int layer = b >> 7;
        const int j = b & 127;
        const PrepSet S = P.s[layer];
        const int NKK = S.K >> 5;
        const int colblk = j >> 5;
        const int n   = (j >> 4) & 1;
        const int lrow = j & 15;
        float acc = 0.0f;
        for (int k = t; k < S.K; k += 256) {
            float rs = rsqrtf(S.v[k] + BN_EPS) * S.g[k];
            float w  = S.W[(size_t)k * 128 + j];
            int kk     = k >> 5;
            int lanehi = (k >> 3) & 3;
            int elem   = k & 7;
            int lane   = lanehi * 16 + lrow;
            size_t idx = ((size_t)((colblk * NKK + kk) * 2 + n) * 64 + lane) * 8 + elem;
            S.WT[idx] = (_Float16)(rs * w);
            acc += (S.b[k] - S.m[k] * rs) * w;
        }
        red[t] = acc;
        __syncthreads();
        #pragma unroll
        for (int s = 128; s > 0; s >>= 1) {
            if (t < s) red[t] += red[t + s];
            __syncthreads();
        }
        if (t == 0) S.bout[j] = S.bias[j] + red[0];
        return;
    }

    if (b < 800) {                       // ---- out_W fragment-linear ----
        const int j = b - 768;           // 0..31
        if (t < 128) {
            int k = t;
            float w = outW[(size_t)k * 32 + j];
            int kk     = k >> 5;
            int lanehi = (k >> 3) & 3;
            int elem   = k & 7;
            int lane   = lanehi * 16 + (j & 15);
            int n      = (j >> 4) & 1;
            size_t idx = ((size_t)(kk * 2 + n) * 64 + lane) * 8 + elem;
            WTc[idx] = (_Float16)w;
        }
        if (t == 0) pbC[j] = outB[j];
        return;
    }

    // ---- bin_count ----
    const int wg = b - 800;
    int* lh = (int*)red;
    lh[t] = 0;
    __syncthreads();
    const int lo = wg * EB_CHUNK;
    const int hi = min(lo + EB_CHUNK, E);
    for (int e = lo + t; e < hi; e += 256)
        atomicAdd(&lh[esrc[e] >> 8], 1);
    __syncthreads();
    hist[t * NWG + wg] = lh[t];
}

// ---------------- fused double FFN (+optional scatter blocks, +fused final C)
template<typename TIn, bool HAS_OUT1, bool DO_SCATTER, bool FUSE_C>
__global__ __launch_bounds__(256) void ffn2_mfma(
    const TIn* __restrict__ x1, int K1,
    const _Float16* __restrict__ x2,
    const _Float16* __restrict__ WTa, const float* __restrict__ biasa,
    const _Float16* __restrict__ WTb, const float* __restrict__ biasb,
    _Float16* __restrict__ out1,
    _Float16* __restrict__ out2, int N,
    const int* __restrict__ esrc, const int* __restrict__ edst,
    const int* __restrict__ hist, const int* __restrict__ rowsum,
    unsigned int* __restrict__ bucketed, int E, int NWG,
    const _Float16* __restrict__ WTc, const float* __restrict__ pbC,
    float* __restrict__ outC)
{
    constexpr int K   = 256;
    constexpr int KB  = 512;
    constexpr int CPR = 32;
    constexpr int NKA = 8;
    constexpr int KB2 = 256;
    constexpr int NKB = 4;
    __shared__ __align__(16) char xs[64 * KB];

    const int tid  = threadIdx.x;

    if constexpr (DO_SCATTER) {          // extra blocks: bin_scatter
        const int nffn = (N + 63) >> 6;
        if ((int)blockIdx.x >= nffn) {
            const int wg = blockIdx.x - nffn;
            int* sh  = (int*)xs;          // 256 scan
            int* cur = sh + 256;
            int v = rowsum[tid];
            sh[tid] = v;
            __syncthreads();
            #pragma unroll
            for (int off = 1; off < 256; off <<= 1) {
                int x = (tid >= off) ? sh[tid - off] : 0;
                __syncthreads();
                sh[tid] += x;
                __syncthreads();
            }
            cur[tid] = hist[tid * NWG + wg] + (sh[tid] - v);  // + bbase[tid]
            __syncthreads();
            const int lo = wg * EB_CHUNK;
            const int hi = min(lo + EB_CHUNK, E);
            for (int e = lo + tid; e < hi; e += 256) {
                int s = esrc[e];
                int pos = atomicAdd(&cur[s >> 8], 1);
                bucketed[pos] = ((unsigned)s << 16) | (unsigned)edst[e];
            }
            return;
        }
    }

    const int row0 = blockIdx.x * 64;
    const int wave = tid >> 6;
    const int lane = tid & 63;
    const int lrow = lane & 15;
    const int lj   = lane >> 4;
    const int lk   = lj * 8;
    const int colbase = wave * 32;

    const _Float16* wfA = WTa + (size_t)wave * NKA * 2 * 512 + lane * 8;
    const _Float16* wfB = WTb + (size_t)wave * NKB * 2 * 512 + lane * 8;

    // ---- stage 64 x 256 fp16 into LDS (swizzled slot = chunk ^ (r&7)) ----
    bool gload = false;
    if constexpr (sizeof(TIn) == 2) {
        if (row0 + 64 <= N) {
            gload = true;
            #pragma unroll
            for (int i = 0; i < 8; ++i) {
                int r  = (wave << 4) + i * 2 + (lane >> 5);
                int j  = lane & 31;
                int cs = j ^ (r & 7);
                const _Float16* g = (cs * 8 < K1)
                    ? (const _Float16*)x1 + (size_t)(row0 + r) * K1 + cs * 8
                    : x2 + (size_t)(row0 + r) * (K - K1) + (cs * 8 - K1);
                char* ldsbase = &xs[(wave << 13) + i * 1024];
                __builtin_amdgcn_global_load_lds(
                    (const __attribute__((address_space(1))) void*)g,
                    (__attribute__((address_space(3))) void*)ldsbase,
                    16, 0, 0);
            }
        }
    }
    if (!gload) {
        for (int c = tid; c < 64 * CPR; c += 256) {
            int r  = c / CPR;
            int kc = c % CPR;
            int k0 = kc * 8;
            int row = row0 + r;
            f16x8 h;
            #pragma unroll
            for (int i = 0; i < 8; ++i) h[i] = (_Float16)0.0f;
            if (row < N) {
                if (k0 < K1) {
                    const TIn* p = x1 + (size_t)row * K1 + k0;
                    if constexpr (sizeof(TIn) == 2) {
                        h = *reinterpret_cast<const f16x8*>(p);
                    } else {
                        const float4 a = *reinterpret_cast<const float4*>(p);
                        const float4 b = *reinterpret_cast<const float4*>(p + 4);
                        h[0]=(_Float16)a.x; h[1]=(_Float16)a.y; h[2]=(_Float16)a.z; h[3]=(_Float16)a.w;
                        h[4]=(_Float16)b.x; h[5]=(_Float16)b.y; h[6]=(_Float16)b.z; h[7]=(_Float16)b.w;
                    }
                } else {
                    h = *reinterpret_cast<const f16x8*>(
                        x2 + (size_t)row * (K - K1) + (k0 - K1));
                }
            }
            int byte = r * KB + ((k0 * 2) ^ ((r & 7) << 4));
            *reinterpret_cast<f16x8*>(&xs[byte]) = h;
        }
    }

    f16x8 fr[2][2];
    fr[0][0] = *reinterpret_cast<const f16x8*>(wfA + 0 * 512);
    fr[0][1] = *reinterpret_cast<const f16x8*>(wfA + 1 * 512);

    __syncthreads();

    f32x4 acc[4][2];
    #pragma unroll
    for (int m = 0; m < 4; ++m) {
        acc[m][0] = (f32x4){0.f,0.f,0.f,0.f};
        acc[m][1] = (f32x4){0.f,0.f,0.f,0.f};
    }

    // ---- layer A: 1-deep pipelined over 8 K-steps ----
    #pragma unroll
    for (int kk = 0; kk < NKA; ++kk) {
        if (kk + 1 < NKA) {
            fr[(kk + 1) & 1][0] = *reinterpret_cast<const f16x8*>(wfA + ((kk + 1) * 2 + 0) * 512);
            fr[(kk + 1) & 1][1] = *reinterpret_cast<const f16x8*>(wfA + ((kk + 1) * 2 + 1) * 512);
        }
        #pragma unroll
        for (int m = 0; m < 4; ++m) {
            int r  = m * 16 + lrow;
            int k0 = kk * 32 + lk;
            f16x8 a = *reinterpret_cast<const f16x8*>(
                &xs[r * KB + ((k0 * 2) ^ ((lrow & 7) << 4))]);
            acc[m][0] = __builtin_amdgcn_mfma_f32_16x16x32_f16(a, fr[kk & 1][0], acc[m][0], 0, 0, 0);
            acc[m][1] = __builtin_amdgcn_mfma_f32_16x16x32_f16(a, fr[kk & 1][1], acc[m][1], 0, 0, 0);
        }
    }

    f16x8 fb[2][2];
    fb[0][0] = *reinterpret_cast<const f16x8*>(wfB + 0 * 512);
    fb[0][1] = *reinterpret_cast<const f16x8*>(wfB + 1 * 512);

    // epilogue A: activation -> (optional) global + mid-LDS (layer-B layout)
    const float ba0 = biasa[colbase + lrow];
    const float ba1 = biasa[colbase + 16 + lrow];
    __syncthreads();   // all layer-A ds_reads complete before overwriting xs
    #pragma unroll
    for (int m = 0; m < 4; ++m) {
        #pragma unroll
        for (int j = 0; j < 4; ++j) {
            int lrowq = m * 16 + lj * 4 + j;
            float v0 = gelu_fast(acc[m][0][j] + ba0);
            float v1 = gelu_fast(acc[m][1][j] + ba1);
            if constexpr (HAS_OUT1) {
                if (row0 + lrowq < N) {
                    _Float16* o = out1 + (size_t)(row0 + lrowq) * 128 + colbase + lrow;
                    o[0]  = (_Float16)v0;
                    o[16] = (_Float16)v1;
                }
            }
            int c0 = (colbase + lrow) * 2;
            int c1 = (colbase + 16 + lrow) * 2;
            int swz = (lrowq & 7) << 4;
            *reinterpret_cast<_Float16*>(&xs[lrowq * KB2 + (c0 ^ swz)]) = (_Float16)v0;
            *reinterpret_cast<_Float16*>(&xs[lrowq * KB2 + (c1 ^ swz)]) = (_Float16)v1;
        }
    }
    __syncthreads();

    #pragma unroll
    for (int m = 0; m < 4; ++m) {
        acc[m][0] = (f32x4){0.f,0.f,0.f,0.f};
        acc[m][1] = (f32x4){0.f,0.f,0.f,0.f};
    }

    // ---- layer B: 1-deep pipelined over 4 K-steps ----
    #pragma unroll
    for (int kk = 0; kk < NKB; ++kk) {
        if (kk + 1 < NKB) {
            fb[(kk + 1) & 1][0] = *reinterpret_cast<const f16x8*>(wfB + ((kk + 1) * 2 + 0) * 512);
            fb[(kk + 1) & 1][1] = *reinterpret_cast<const f16x8*>(wfB + ((kk + 1) * 2 + 1) * 512);
        }
        #pragma unroll
        for (int m = 0; m < 4; ++m) {
            int r  = m * 16 + lrow;
            int k0 = kk * 32 + lk;
            f16x8 a = *reinterpret_cast<const f16x8*>(
                &xs[r * KB2 + ((k0 * 2) ^ ((lrow & 7) << 4))]);
            acc[m][0] = __builtin_amdgcn_mfma_f32_16x16x32_f16(a, fb[kk & 1][0], acc[m][0], 0, 0, 0);
            acc[m][1] = __builtin_amdgcn_mfma_f32_16x16x32_f16(a, fb[kk & 1][1], acc[m][1], 0, 0, 0);
        }
    }

    const float bb0 = biasb[colbase + lrow];
    const float bb1 = biasb[colbase + 16 + lrow];

    if constexpr (!FUSE_C) {
        // epilogue B: gelu -> global fp16 (direct register stores)
        #pragma unroll
        for (int m = 0; m < 4; ++m) {
            #pragma unroll
            for (int j = 0; j < 4; ++j) {
                int grow = row0 + m * 16 + lj * 4 + j;
                if (grow >= N) continue;
                _Float16* o = out2 + (size_t)grow * 128 + colbase + lrow;
                o[0]  = (_Float16)gelu_fast(acc[m][0][j] + bb0);
                o[16] = (_Float16)gelu_fast(acc[m][1][j] + bb1);
            }
        }
    } else {
        // epilogue B: gelu -> LDS (layer-C input), then fused final linear
        __syncthreads();
        #pragma unroll
        for (int m = 0; m < 4; ++m) {
            #pragma unroll
            for (int j = 0; j < 4; ++j) {
                int lrowq = m * 16 + lj * 4 + j;
                float v0 = gelu_fast(acc[m][0][j] + bb0);
                float v1 = gelu_fast(acc[m][1][j] + bb1);
                int c0 = (colbase + lrow) * 2;
                int c1 = (colbase + 16 + lrow) * 2;
                int swz = (lrowq & 7) << 4;
                *reinterpret_cast<_Float16*>(&xs[lrowq * KB2 + (c0 ^ swz)]) = (_Float16)v0;
                *reinterpret_cast<_Float16*>(&xs[lrowq * KB2 + (c1 ^ swz)]) = (_Float16)v1;
            }
        }
        __syncthreads();

        // layer C: each wave owns rows [wave*16, wave*16+16), 32 cols
        const _Float16* wfC = WTc + lane * 8;
        f32x4 accC[2];
        accC[0] = (f32x4){0.f,0.f,0.f,0.f};
        accC[1] = (f32x4){0.f,0.f,0.f,0.f};
        #pragma unroll
        for (int kk = 0; kk < 4; ++kk) {
            int r  = wave * 16 + lrow;
            int k0 = kk * 32 + lk;
            f16x8 a = *reinterpret_cast<const f16x8*>(
                &xs[r * KB2 + ((k0 * 2) ^ ((lrow & 7) << 4))]);
            f16x8 c0 = *reinterpret_cast<const f16x8*>(wfC + (kk * 2 + 0) * 512);
            f16x8 c1 = *reinterpret_cast<const f16x8*>(wfC + (kk * 2 + 1) * 512);
            accC[0] = __builtin_amdgcn_mfma_f32_16x16x32_f16(a, c0, accC[0], 0, 0, 0);
            accC[1] = __builtin_amdgcn_mfma_f32_16x16x32_f16(a, c1, accC[1], 0, 0, 0);
        }
        const float bc0 = pbC[lrow];
        const float bc1 = pbC[16 + lrow];
        #pragma unroll
        for (int j = 0; j < 4; ++j) {
            int grow = row0 + wave * 16 + lj * 4 + j;
            if (grow >= N) continue;
            float* o = outC + (size_t)grow * 32 + lrow;
            o[0]  = accC[0][j] + bc0;
            o[16] = accC[1][j] + bc1;
        }
    }
}

// ---------------- CSR: per-bin chunk scan (hist cursors + rowsum) -----------
__global__ __launch_bounds__(256) void bin_row_scan(
    int* __restrict__ hist, int* __restrict__ rowsum, int NWG)
{
    __shared__ int sh[256];
    const int t = threadIdx.x;
    const int b = blockIdx.x;
    int v = (t < NWG) ? hist[b * NWG + t] : 0;
    sh[t] = v;
    __syncthreads();
    #pragma unroll
    for (int off = 1; off < 256; off <<= 1) {
        int x = (t >= off) ? sh[t - off] : 0;
        __syncthreads();
        sh[t] += x;
        __syncthreads();
    }
    if (t < NWG) hist[b * NWG + t] = sh[t] - v;
    if (t == 255) rowsum[b] = sh[255];
}

// per bucket: recompute bbase locally from rowsum (no serial bbase_scan)
__global__ __launch_bounds__(256) void bucket_csr(
    const unsigned int* __restrict__ bucketed, const int* __restrict__ rowsum,
    int* __restrict__ offs, int* __restrict__ csr_dst, int N)
{
    __shared__ int sh[256];
    __shared__ int exc[256];
    __shared__ int cnt[256];
    __shared__ int sc[256];
    __shared__ int cur[256];
    const int t = threadIdx.x;
    const int b = blockIdx.x;

    int v = rowsum[t];
    sh[t] = v;
    __syncthreads();
    #pragma unroll
    for (int off = 1; off < 256; off <<= 1) {
        int x = (t >= off) ? sh[t - off] : 0;
        __syncthreads();
        sh[t] += x;
        __syncthreads();
    }
    exc[t] = sh[t] - v;
    __syncthreads();
    const int base = exc[b];
    const int bsz  = rowsum[b];

    cnt[t] = 0;
    __syncthreads();
    for (int i = t; i < bsz; i += 256) {
        unsigned key = bucketed[base + i];
        atomicAdd(&cnt[(key >> 16) & 255], 1);
    }
    __syncthreads();
    int c = cnt[t];
    sc[t] = c;
    __syncthreads();
    #pragma unroll
    for (int off = 1; off < 256; off <<= 1) {
        int x = (t >= off) ? sc[t - off] : 0;
        __syncthreads();
        sc[t] += x;
        __syncthreads();
    }
    int myoff = sc[t] - c;
    cur[t] = myoff;
    int node = b * 256 + t;
    if (node <= N) offs[node] = base + myoff;
    __syncthreads();
    for (int i = t; i < bsz; i += 256) {
        unsigned key = bucketed[base + i];
        int sl = (key >> 16) & 255;
        int pos = base + atomicAdd(&cur[sl], 1);
        csr_dst[pos] = (int)(key & 0xFFFFu);
    }
}

// one wave per node, 4 neighbors per load step (16 lanes x 16B each = 1 row).
__global__ __launch_bounds__(256) void aggregate_kernel(
    const _Float16* __restrict__ y,
    const int* __restrict__ csr_dst, const int* __restrict__ offs,
    _Float16* __restrict__ agg, int N)
{
    const int wave = (blockIdx.x * blockDim.x + threadIdx.x) >> 6;
    const int lane = threadIdx.x & 63;
    if (wave >= N) return;
    const int lo = offs[wave];
    const int hi = offs[wave + 1];
    const int sub = lane >> 4;
    const int col = (lane & 15) * 8;

    float a[8];
    #pragma unroll
    for (int j = 0; j < 8; ++j) a[j] = 0.0f;

    for (int base = lo; base < hi; base += 64) {
        int myd = (base + lane < hi) ? csr_dst[base + lane] : -1;
        int m = hi - base;
        if (m > 64) m = 64;
        int ng = (m + 3) >> 2;
        #pragma unroll 8
        for (int i = 0; i < ng; ++i) {
            int d = __shfl(myd, i * 4 + sub);
            if (d >= 0) {
                f16x8 v = *reinterpret_cast<const f16x8*>(
                    y + (size_t)d * 128 + col);
                #pragma unroll
                for (int j = 0; j < 8; ++j) a[j] += (float)v[j];
            }
        }
    }

    #pragma unroll
    for (int j = 0; j < 8; ++j) {
        a[j] += __shfl_xor(a[j], 16);
        a[j] += __shfl_xor(a[j], 32);
    }

    if (lane < 16) {
        const float inv = (hi > lo) ? 1.0f / (float)(hi - lo) : 0.0f;
        f16x8 o;
        #pragma unroll
        for (int j = 0; j < 8; ++j) o[j] = (_Float16)(a[j] * inv);
        *reinterpret_cast<f16x8*>(agg + (size_t)wave * 128 + col) = o;
    }
}

extern "C" void kernel_launch(void* const* d_in, const int* in_sizes, int n_in,
                              void* d_out, int out_size, void* d_ws, size_t ws_size,
                              hipStream_t stream) {
    const float* nf   = (const float*)d_in[0];
    const int*   esrc = (const int*)d_in[1];
    const int*   edst = (const int*)d_in[2];
    auto in = [&](int i) { return (const float*)d_in[i]; };

    const int N = in_sizes[3];       // 50000
    const int E = in_sizes[1];       // 800000
    const int H = 128;

    _Float16* xA  = (_Float16*)d_ws;
    _Float16* xB  = xA + (size_t)N * H;
    _Float16* y   = xB + (size_t)N * H;
    _Float16* agg = y  + (size_t)N * H;

    _Float16* WT0 = agg + (size_t)N * H;                // pre   256x128
    _Float16* WT2 = WT0 + 256 * 128;                    // c1u   256x128
    _Float16* WT4 = WT2 + 256 * 128;                    // c2u   256x128
    _Float16* WT1 = WT4 + 256 * 128;                    // c1p   128x128
    _Float16* WT3 = WT1 + 128 * 128;                    // c2p   128x128
    _Float16* WT5 = WT3 + 128 * 128;                    // post  128x128
    _Float16* WTc = WT5 + 128 * 128;                    // out   128x32 frag-linear
    float* pb     = (float*)(WTc + 4096);               // 6 x 128 biases
    float* pbC    = pb + 6 * 128;                       // 32

    const int NWG = (E + EB_CHUNK - 1) / EB_CHUNK;      // 196
    const int NB  = (N + 255) >> 8;                     // 196 buckets

    int* hist      = (int*)(pbC + 32);                  // 256 * NWG
    int* rowsum    = hist + 256 * NWG;                  // 256
    int* offs      = rowsum + 256;                      // N+1
    int* csr_dst   = offs + (N + 1);                    // E
    unsigned int* bucketed = (unsigned int*)(csr_dst + E);  // E

    const int ffnGrid = (N + 63) / 64;

    // ---- weight prep + out_W prep + bin_count, one launch ----
    PrepAll P;
    const float* base[6][6] = {
        { in(4),  in(5),  in(6),  in(7),  in(8),  in(9)  },   // pre  K=256
        { in(10), in(11), in(12), in(13), in(14), in(15) },   // c1p  K=128
        { in(16), in(17), in(18), in(19), in(20), in(21) },   // c1u  K=256
        { in(22), in(23), in(24), in(25), in(26), in(27) },   // c2p  K=128
        { in(28), in(29), in(30), in(31), in(32), in(33) },   // c2u  K=256
        { in(34), in(35), in(36), in(37), in(38), in(39) },   // post K=128
    };
    _Float16* wt[6] = { WT0, WT1, WT2, WT3, WT4, WT5 };
    const int  kk[6] = { 256, 128, 256, 128, 256, 128 };
    for (int l = 0; l < 6; ++l) {
        P.s[l].g = base[l][0]; P.s[l].b = base[l][1]; P.s[l].m = base[l][2];
        P.s[l].v = base[l][3]; P.s[l].W = base[l][4]; P.s[l].bias = base[l][5];
        P.s[l].WT = wt[l]; P.s[l].bout = pb + l * 128; P.s[l].K = kk[l];
    }
    prep_fat<<<800 + NWG, 256, 0, stream>>>(
        P, in(40), in(41), WTc, pbC, esrc, hist, E, NWG);

    bin_row_scan<<<256, 256, 0, stream>>>(hist, rowsum, NWG);

    // ---- F1: pre + c1p (nf f32 -> xA, y)  ||  bin_scatter (extra blocks) ----
    ffn2_mfma<float, true, true, false><<<ffnGrid + NWG, 256, 0, stream>>>(
        nf, 256, nullptr, WT0, pb + 0*128, WT1, pb + 1*128, xA, y, N,
        esrc, edst, hist, rowsum, bucketed, E, NWG, nullptr, nullptr, nullptr);

    bucket_csr<<<NB, 256, 0, stream>>>(bucketed, rowsum, offs, csr_dst, N);

    // ---- conv1 aggregate ----
    aggregate_kernel<<<(N * 64 + 255) / 256, 256, 0, stream>>>(y, csr_dst, offs, agg, N);

    // ---- F2: c1u + c2p ([xA,agg] -> xB, y) ----
    ffn2_mfma<_Float16, true, false, false><<<ffnGrid, 256, 0, stream>>>(
        xA, 128, agg, WT2, pb + 2*128, WT3, pb + 3*128, xB, y, N,
        nullptr, nullptr, nullptr, nullptr, nullptr, 0, 0, nullptr, nullptr, nullptr);

    // ---- conv2 aggregate ----
    aggregate_kernel<<<(N * 64 + 255) / 256, 256, 0, stream>>>(y, csr_dst, offs, agg, N);

    // ---- F3: c2u + post + fused final linear -> d_out (fp32) ----
    ffn2_mfma<_Float16, false, false, true><<<ffnGrid, 256, 0, stream>>>(
        xB, 128, agg, WT4, pb + 4*128, WT5, pb + 5*128, nullptr, nullptr, N,
        nullptr, nullptr, nullptr, nullptr, nullptr, 0, 0, WTc, pbC, (float*)d_out);
}

// Round 21
// 154.363 us; speedup vs baseline: 1.0377x; 1.0145x over previous
//
#include <hip/hip_runtime.h>
#include <math.h>

#define BN_EPS 1e-5f
#define EB_CHUNK 4096

typedef _Float16 f16x8 __attribute__((ext_vector_type(8)));
typedef float f32x4 __attribute__((ext_vector_type(4)));

__device__ __forceinline__ float gelu_fast(float x) {
    float z  = x * 0.7071067811865475f;
    float az = fabsf(z);
    float t  = __builtin_amdgcn_rcpf(1.0f + 0.3275911f * az);
    float poly = t * (0.254829592f + t * (-0.284496736f + t * (1.421413741f +
                 t * (-1.453152027f + t * 1.061405429f))));
    float e = __expf(-z * z);
    float erfv = copysignf(1.0f - poly * e, z);
    return 0.5f * x * (1.0f + erfv);
}

// ---------------- fat prep: BN-fold 6 layers (fragment-linear) + out_W prep
// + bin_count, one launch ---------------------------------------------------
struct PrepSet {
    const float *g, *b, *m, *v, *W, *bias;
    _Float16* WT;
    float* bout;
    int K;
};
struct PrepAll { PrepSet s[6]; };

__global__ __launch_bounds__(256) void prep_fat(
    PrepAll P,
    const float* __restrict__ outW, const float* __restrict__ outB,
    _Float16* __restrict__ WTc, float* __restrict__ pbC,
    const int* __restrict__ esrc, int* __restrict__ hist, int E, int NWG)
{
    __shared__ float red[256];
    const int b = blockIdx.x;
    const int t = threadIdx.x;

    if (b < 768) {                       // ---- BN-folded layer weights ----
        const int layer = b >> 7;
        const int j = b & 127;
        const PrepSet S = P.s[layer];
        const int NKK = S.K >> 5;
        const int colblk = j >> 5;
        const int n   = (j >> 4) & 1;
        const int lrow = j & 15;
        float acc = 0.0f;
        for (int k = t; k < S.K; k += 256) {
            float rs = rsqrtf(S.v[k] + BN_EPS) * S.g[k];
            float w  = S.W[(size_t)k * 128 + j];
            int kk     = k >> 5;
            int lanehi = (k >> 3) & 3;
            int elem   = k & 7;
            int lane   = lanehi * 16 + lrow;
            size_t idx = ((size_t)((colblk * NKK + kk) * 2 + n) * 64 + lane) * 8 + elem;
            S.WT[idx] = (_Float16)(rs * w);
            acc += (S.b[k] - S.m[k] * rs) * w;
        }
        red[t] = acc;
        __syncthreads();
        #pragma unroll
        for (int s = 128; s > 0; s >>= 1) {
            if (t < s) red[t] += red[t + s];
            __syncthreads();
        }
        if (t == 0) S.bout[j] = S.bias[j] + red[0];
        return;
    }

    if (b < 800) {                       // ---- out_W fragment-linear ----
        const int j = b - 768;           // 0..31
        if (t < 128) {
            int k = t;
            float w = outW[(size_t)k * 32 + j];
            int kk     = k >> 5;
            int lanehi = (k >> 3) & 3;
            int elem   = k & 7;
            int lane   = lanehi * 16 + (j & 15);
            int n      = (j >> 4) & 1;
            size_t idx = ((size_t)(kk * 2 + n) * 64 + lane) * 8 + elem;
            WTc[idx] = (_Float16)w;
        }
        if (t == 0) pbC[j] = outB[j];
        return;
    }

    // ---- bin_count ----
    const int wg = b - 800;
    int* lh = (int*)red;
    lh[t] = 0;
    __syncthreads();
    const int lo = wg * EB_CHUNK;
    const int hi = min(lo + EB_CHUNK, E);
    for (int e = lo + t; e < hi; e += 256)
        atomicAdd(&lh[esrc[e] >> 8], 1);
    __syncthreads();
    hist[t * NWG + wg] = lh[t];
}

// ---------------- fused double FFN (+optional scatter blocks, +fused final C)
// out1 stores DEFERRED to kernel end so no barrier drains them (the epilogue-A
// __syncthreads otherwise waits vmcnt(0) on 8192 scalar stores per block).
template<typename TIn, bool HAS_OUT1, bool DO_SCATTER, bool FUSE_C>
__global__ __launch_bounds__(256) void ffn2_mfma(
    const TIn* __restrict__ x1, int K1,
    const _Float16* __restrict__ x2,
    const _Float16* __restrict__ WTa, const float* __restrict__ biasa,
    const _Float16* __restrict__ WTb, const float* __restrict__ biasb,
    _Float16* __restrict__ out1,
    _Float16* __restrict__ out2, int N,
    const int* __restrict__ esrc, const int* __restrict__ edst,
    const int* __restrict__ hist, const int* __restrict__ rowsum,
    unsigned int* __restrict__ bucketed, int E, int NWG,
    const _Float16* __restrict__ WTc, const float* __restrict__ pbC,
    float* __restrict__ outC)
{
    constexpr int K   = 256;
    constexpr int KB  = 512;
    constexpr int CPR = 32;
    constexpr int NKA = 8;
    constexpr int KB2 = 256;
    constexpr int NKB = 4;
    __shared__ __align__(16) char xs[64 * KB];

    const int tid  = threadIdx.x;

    if constexpr (DO_SCATTER) {          // extra blocks: bin_scatter
        const int nffn = (N + 63) >> 6;
        if ((int)blockIdx.x >= nffn) {
            const int wg = blockIdx.x - nffn;
            int* sh  = (int*)xs;          // 256 scan
            int* cur = sh + 256;
            int v = rowsum[tid];
            sh[tid] = v;
            __syncthreads();
            #pragma unroll
            for (int off = 1; off < 256; off <<= 1) {
                int x = (tid >= off) ? sh[tid - off] : 0;
                __syncthreads();
                sh[tid] += x;
                __syncthreads();
            }
            cur[tid] = hist[tid * NWG + wg] + (sh[tid] - v);  // + bbase[tid]
            __syncthreads();
            const int lo = wg * EB_CHUNK;
            const int hi = min(lo + EB_CHUNK, E);
            for (int e = lo + tid; e < hi; e += 256) {
                int s = esrc[e];
                int pos = atomicAdd(&cur[s >> 8], 1);
                bucketed[pos] = ((unsigned)s << 16) | (unsigned)edst[e];
            }
            return;
        }
    }

    const int row0 = blockIdx.x * 64;
    const int wave = tid >> 6;
    const int lane = tid & 63;
    const int lrow = lane & 15;
    const int lj   = lane >> 4;
    const int lk   = lj * 8;
    const int colbase = wave * 32;

    const _Float16* wfA = WTa + (size_t)wave * NKA * 2 * 512 + lane * 8;
    const _Float16* wfB = WTb + (size_t)wave * NKB * 2 * 512 + lane * 8;

    // ---- stage 64 x 256 fp16 into LDS (swizzled slot = chunk ^ (r&7)) ----
    bool gload = false;
    if constexpr (sizeof(TIn) == 2) {
        if (row0 + 64 <= N) {
            gload = true;
            #pragma unroll
            for (int i = 0; i < 8; ++i) {
                int r  = (wave << 4) + i * 2 + (lane >> 5);
                int j  = lane & 31;
                int cs = j ^ (r & 7);
                const _Float16* g = (cs * 8 < K1)
                    ? (const _Float16*)x1 + (size_t)(row0 + r) * K1 + cs * 8
                    : x2 + (size_t)(row0 + r) * (K - K1) + (cs * 8 - K1);
                char* ldsbase = &xs[(wave << 13) + i * 1024];
                __builtin_amdgcn_global_load_lds(
                    (const __attribute__((address_space(1))) void*)g,
                    (__attribute__((address_space(3))) void*)ldsbase,
                    16, 0, 0);
            }
        }
    }
    if (!gload) {
        for (int c = tid; c < 64 * CPR; c += 256) {
            int r  = c / CPR;
            int kc = c % CPR;
            int k0 = kc * 8;
            int row = row0 + r;
            f16x8 h;
            #pragma unroll
            for (int i = 0; i < 8; ++i) h[i] = (_Float16)0.0f;
            if (row < N) {
                if (k0 < K1) {
                    const TIn* p = x1 + (size_t)row * K1 + k0;
                    if constexpr (sizeof(TIn) == 2) {
                        h = *reinterpret_cast<const f16x8*>(p);
                    } else {
                        const float4 a = *reinterpret_cast<const float4*>(p);
                        const float4 b = *reinterpret_cast<const float4*>(p + 4);
                        h[0]=(_Float16)a.x; h[1]=(_Float16)a.y; h[2]=(_Float16)a.z; h[3]=(_Float16)a.w;
                        h[4]=(_Float16)b.x; h[5]=(_Float16)b.y; h[6]=(_Float16)b.z; h[7]=(_Float16)b.w;
                    }
                } else {
                    h = *reinterpret_cast<const f16x8*>(
                        x2 + (size_t)row * (K - K1) + (k0 - K1));
                }
            }
            int byte = r * KB + ((k0 * 2) ^ ((r & 7) << 4));
            *reinterpret_cast<f16x8*>(&xs[byte]) = h;
        }
    }

    f16x8 fr[2][2];
    fr[0][0] = *reinterpret_cast<const f16x8*>(wfA + 0 * 512);
    fr[0][1] = *reinterpret_cast<const f16x8*>(wfA + 1 * 512);

    __syncthreads();

    f32x4 acc[4][2];
    #pragma unroll
    for (int m = 0; m < 4; ++m) {
        acc[m][0] = (f32x4){0.f,0.f,0.f,0.f};
        acc[m][1] = (f32x4){0.f,0.f,0.f,0.f};
    }

    // ---- layer A: 1-deep pipelined over 8 K-steps ----
    #pragma unroll
    for (int kk = 0; kk < NKA; ++kk) {
        if (kk + 1 < NKA) {
            fr[(kk + 1) & 1][0] = *reinterpret_cast<const f16x8*>(wfA + ((kk + 1) * 2 + 0) * 512);
            fr[(kk + 1) & 1][1] = *reinterpret_cast<const f16x8*>(wfA + ((kk + 1) * 2 + 1) * 512);
        }
        #pragma unroll
        for (int m = 0; m < 4; ++m) {
            int r  = m * 16 + lrow;
            int k0 = kk * 32 + lk;
            f16x8 a = *reinterpret_cast<const f16x8*>(
                &xs[r * KB + ((k0 * 2) ^ ((lrow & 7) << 4))]);
            acc[m][0] = __builtin_amdgcn_mfma_f32_16x16x32_f16(a, fr[kk & 1][0], acc[m][0], 0, 0, 0);
            acc[m][1] = __builtin_amdgcn_mfma_f32_16x16x32_f16(a, fr[kk & 1][1], acc[m][1], 0, 0, 0);
        }
    }

    f16x8 fb[2][2];
    fb[0][0] = *reinterpret_cast<const f16x8*>(wfB + 0 * 512);
    fb[0][1] = *reinterpret_cast<const f16x8*>(wfB + 1 * 512);

    // epilogue A: gelu -> mid-LDS only; out1 values HELD in registers
    _Float16 o1v[4][4][2];   // 16 VGPRs when HAS_OUT1
    const float ba0 = biasa[colbase + lrow];
    const float ba1 = biasa[colbase + 16 + lrow];
    __syncthreads();   // all layer-A ds_reads complete before overwriting xs
    #pragma unroll
    for (int m = 0; m < 4; ++m) {
        #pragma unroll
        for (int j = 0; j < 4; ++j) {
            int lrowq = m * 16 + lj * 4 + j;
            float v0 = gelu_fast(acc[m][0][j] + ba0);
            float v1 = gelu_fast(acc[m][1][j] + ba1);
            _Float16 h0 = (_Float16)v0;
            _Float16 h1 = (_Float16)v1;
            if constexpr (HAS_OUT1) {
                o1v[m][j][0] = h0;
                o1v[m][j][1] = h1;
            }
            int c0 = (colbase + lrow) * 2;
            int c1 = (colbase + 16 + lrow) * 2;
            int swz = (lrowq & 7) << 4;
            *reinterpret_cast<_Float16*>(&xs[lrowq * KB2 + (c0 ^ swz)]) = h0;
            *reinterpret_cast<_Float16*>(&xs[lrowq * KB2 + (c1 ^ swz)]) = h1;
        }
    }
    __syncthreads();   // drains only LDS writes now (no global stores pending)

    #pragma unroll
    for (int m = 0; m < 4; ++m) {
        acc[m][0] = (f32x4){0.f,0.f,0.f,0.f};
        acc[m][1] = (f32x4){0.f,0.f,0.f,0.f};
    }

    // ---- layer B: 1-deep pipelined over 4 K-steps ----
    #pragma unroll
    for (int kk = 0; kk < NKB; ++kk) {
        if (kk + 1 < NKB) {
            fb[(kk + 1) & 1][0] = *reinterpret_cast<const f16x8*>(wfB + ((kk + 1) * 2 + 0) * 512);
            fb[(kk + 1) & 1][1] = *reinterpret_cast<const f16x8*>(wfB + ((kk + 1) * 2 + 1) * 512);
        }
        #pragma unroll
        for (int m = 0; m < 4; ++m) {
            int r  = m * 16 + lrow;
            int k0 = kk * 32 + lk;
            f16x8 a = *reinterpret_cast<const f16x8*>(
                &xs[r * KB2 + ((k0 * 2) ^ ((lrow & 7) << 4))]);
            acc[m][0] = __builtin_amdgcn_mfma_f32_16x16x32_f16(a, fb[kk & 1][0], acc[m][0], 0, 0, 0);
            acc[m][1] = __builtin_amdgcn_mfma_f32_16x16x32_f16(a, fb[kk & 1][1], acc[m][1], 0, 0, 0);
        }
    }

    const float bb0 = biasb[colbase + lrow];
    const float bb1 = biasb[colbase + 16 + lrow];

    if constexpr (!FUSE_C) {
        // epilogue B: gelu -> global fp16 (kernel end, no barrier after)
        #pragma unroll
        for (int m = 0; m < 4; ++m) {
            #pragma unroll
            for (int j = 0; j < 4; ++j) {
                int grow = row0 + m * 16 + lj * 4 + j;
                if (grow >= N) continue;
                _Float16* o = out2 + (size_t)grow * 128 + colbase + lrow;
                o[0]  = (_Float16)gelu_fast(acc[m][0][j] + bb0);
                o[16] = (_Float16)gelu_fast(acc[m][1][j] + bb1);
            }
        }
    } else {
        // epilogue B: gelu -> LDS (layer-C input), then fused final linear
        __syncthreads();
        #pragma unroll
        for (int m = 0; m < 4; ++m) {
            #pragma unroll
            for (int j = 0; j < 4; ++j) {
                int lrowq = m * 16 + lj * 4 + j;
                float v0 = gelu_fast(acc[m][0][j] + bb0);
                float v1 = gelu_fast(acc[m][1][j] + bb1);
                int c0 = (colbase + lrow) * 2;
                int c1 = (colbase + 16 + lrow) * 2;
                int swz = (lrowq & 7) << 4;
                *reinterpret_cast<_Float16*>(&xs[lrowq * KB2 + (c0 ^ swz)]) = (_Float16)v0;
                *reinterpret_cast<_Float16*>(&xs[lrowq * KB2 + (c1 ^ swz)]) = (_Float16)v1;
            }
        }
        __syncthreads();

        // layer C: each wave owns rows [wave*16, wave*16+16), 32 cols
        const _Float16* wfC = WTc + lane * 8;
        f32x4 accC[2];
        accC[0] = (f32x4){0.f,0.f,0.f,0.f};
        accC[1] = (f32x4){0.f,0.f,0.f,0.f};
        #pragma unroll
        for (int kk = 0; kk < 4; ++kk) {
            int r  = wave * 16 + lrow;
            int k0 = kk * 32 + lk;
            f16x8 a = *reinterpret_cast<const f16x8*>(
                &xs[r * KB2 + ((k0 * 2) ^ ((lrow & 7) << 4))]);
            f16x8 c0 = *reinterpret_cast<const f16x8*>(wfC + (kk * 2 + 0) * 512);
            f16x8 c1 = *reinterpret_cast<const f16x8*>(wfC + (kk * 2 + 1) * 512);
            accC[0] = __builtin_amdgcn_mfma_f32_16x16x32_f16(a, c0, accC[0], 0, 0, 0);
            accC[1] = __builtin_amdgcn_mfma_f32_16x16x32_f16(a, c1, accC[1], 0, 0, 0);
        }
        const float bc0 = pbC[lrow];
        const float bc1 = pbC[16 + lrow];
        #pragma unroll
        for (int j = 0; j < 4; ++j) {
            int grow = row0 + wave * 16 + lj * 4 + j;
            if (grow >= N) continue;
            float* o = outC + (size_t)grow * 32 + lrow;
            o[0]  = accC[0][j] + bc0;
            o[16] = accC[1][j] + bc1;
        }
    }

    // ---- deferred out1 stores (kernel end: no barrier ever drains these) ----
    if constexpr (HAS_OUT1) {
        #pragma unroll
        for (int m = 0; m < 4; ++m) {
            #pragma unroll
            for (int j = 0; j < 4; ++j) {
                int grow = row0 + m * 16 + lj * 4 + j;
                if (grow >= N) continue;
                _Float16* o = out1 + (size_t)grow * 128 + colbase + lrow;
                o[0]  = o1v[m][j][0];
                o[16] = o1v[m][j][1];
            }
        }
    }
}

// ---------------- CSR: per-bin chunk scan (hist cursors + rowsum) -----------
__global__ __launch_bounds__(256) void bin_row_scan(
    int* __restrict__ hist, int* __restrict__ rowsum, int NWG)
{
    __shared__ int sh[256];
    const int t = threadIdx.x;
    const int b = blockIdx.x;
    int v = (t < NWG) ? hist[b * NWG + t] : 0;
    sh[t] = v;
    __syncthreads();
    #pragma unroll
    for (int off = 1; off < 256; off <<= 1) {
        int x = (t >= off) ? sh[t - off] : 0;
        __syncthreads();
        sh[t] += x;
        __syncthreads();
    }
    if (t < NWG) hist[b * NWG + t] = sh[t] - v;
    if (t == 255) rowsum[b] = sh[255];
}

// per bucket: recompute bbase locally from rowsum (no serial bbase_scan)
__global__ __launch_bounds__(256) void bucket_csr(
    const unsigned int* __restrict__ bucketed, const int* __restrict__ rowsum,
    int* __restrict__ offs, int* __restrict__ csr_dst, int N)
{
    __shared__ int sh[256];
    __shared__ int exc[256];
    __shared__ int cnt[256];
    __shared__ int sc[256];
    __shared__ int cur[256];
    const int t = threadIdx.x;
    const int b = blockIdx.x;

    int v = rowsum[t];
    sh[t] = v;
    __syncthreads();
    #pragma unroll
    for (int off = 1; off < 256; off <<= 1) {
        int x = (t >= off) ? sh[t - off] : 0;
        __syncthreads();
        sh[t] += x;
        __syncthreads();
    }
    exc[t] = sh[t] - v;
    __syncthreads();
    const int base = exc[b];
    const int bsz  = rowsum[b];

    cnt[t] = 0;
    __syncthreads();
    for (int i = t; i < bsz; i += 256) {
        unsigned key = bucketed[base + i];
        atomicAdd(&cnt[(key >> 16) & 255], 1);
    }
    __syncthreads();
    int c = cnt[t];
    sc[t] = c;
    __syncthreads();
    #pragma unroll
    for (int off = 1; off < 256; off <<= 1) {
        int x = (t >= off) ? sc[t - off] : 0;
        __syncthreads();
        sc[t] += x;
        __syncthreads();
    }
    int myoff = sc[t] - c;
    cur[t] = myoff;
    int node = b * 256 + t;
    if (node <= N) offs[node] = base + myoff;
    __syncthreads();
    for (int i = t; i < bsz; i += 256) {
        unsigned key = bucketed[base + i];
        int sl = (key >> 16) & 255;
        int pos = base + atomicAdd(&cur[sl], 1);
        csr_dst[pos] = (int)(key & 0xFFFFu);
    }
}

// one wave per node, 4 neighbors per load step (16 lanes x 16B each = 1 row).
__global__ __launch_bounds__(256) void aggregate_kernel(
    const _Float16* __restrict__ y,
    const int* __restrict__ csr_dst, const int* __restrict__ offs,
    _Float16* __restrict__ agg, int N)
{
    const int wave = (blockIdx.x * blockDim.x + threadIdx.x) >> 6;
    const int lane = threadIdx.x & 63;
    if (wave >= N) return;
    const int lo = offs[wave];
    const int hi = offs[wave + 1];
    const int sub = lane >> 4;
    const int col = (lane & 15) * 8;

    float a[8];
    #pragma unroll
    for (int j = 0; j < 8; ++j) a[j] = 0.0f;

    for (int base = lo; base < hi; base += 64) {
        int myd = (base + lane < hi) ? csr_dst[base + lane] : -1;
        int m = hi - base;
        if (m > 64) m = 64;
        int ng = (m + 3) >> 2;
        #pragma unroll 8
        for (int i = 0; i < ng; ++i) {
            int d = __shfl(myd, i * 4 + sub);
            if (d >= 0) {
                f16x8 v = *reinterpret_cast<const f16x8*>(
                    y + (size_t)d * 128 + col);
                #pragma unroll
                for (int j = 0; j < 8; ++j) a[j] += (float)v[j];
            }
        }
    }

    #pragma unroll
    for (int j = 0; j < 8; ++j) {
        a[j] += __shfl_xor(a[j], 16);
        a[j] += __shfl_xor(a[j], 32);
    }

    if (lane < 16) {
        const float inv = (hi > lo) ? 1.0f / (float)(hi - lo) : 0.0f;
        f16x8 o;
        #pragma unroll
        for (int j = 0; j < 8; ++j) o[j] = (_Float16)(a[j] * inv);
        *reinterpret_cast<f16x8*>(agg + (size_t)wave * 128 + col) = o;
    }
}

extern "C" void kernel_launch(void* const* d_in, const int* in_sizes, int n_in,
                              void* d_out, int out_size, void* d_ws, size_t ws_size,
                              hipStream_t stream) {
    const float* nf   = (const float*)d_in[0];
    const int*   esrc = (const int*)d_in[1];
    const int*   edst = (const int*)d_in[2];
    auto in = [&](int i) { return (const float*)d_in[i]; };

    const int N = in_sizes[3];       // 50000
    const int E = in_sizes[1];       // 800000
    const int H = 128;

    _Float16* xA  = (_Float16*)d_ws;
    _Float16* xB  = xA + (size_t)N * H;
    _Float16* y   = xB + (size_t)N * H;
    _Float16* agg = y  + (size_t)N * H;

    _Float16* WT0 = agg + (size_t)N * H;                // pre   256x128
    _Float16* WT2 = WT0 + 256 * 128;                    // c1u   256x128
    _Float16* WT4 = WT2 + 256 * 128;                    // c2u   256x128
    _Float16* WT1 = WT4 + 256 * 128;                    // c1p   128x128
    _Float16* WT3 = WT1 + 128 * 128;                    // c2p   128x128
    _Float16* WT5 = WT3 + 128 * 128;                    // post  128x128
    _Float16* WTc = WT5 + 128 * 128;                    // out   128x32 frag-linear
    float* pb     = (float*)(WTc + 4096);               // 6 x 128 biases
    float* pbC    = pb + 6 * 128;                       // 32

    const int NWG = (E + EB_CHUNK - 1) / EB_CHUNK;      // 196
    const int NB  = (N + 255) >> 8;                     // 196 buckets

    int* hist      = (int*)(pbC + 32);                  // 256 * NWG
    int* rowsum    = hist + 256 * NWG;                  // 256
    int* offs      = rowsum + 256;                      // N+1
    int* csr_dst   = offs + (N + 1);                    // E
    unsigned int* bucketed = (unsigned int*)(csr_dst + E);  // E

    const int ffnGrid = (N + 63) / 64;

    // ---- weight prep + out_W prep + bin_count, one launch ----
    PrepAll P;
    const float* base[6][6] = {
        { in(4),  in(5),  in(6),  in(7),  in(8),  in(9)  },   // pre  K=256
        { in(10), in(11), in(12), in(13), in(14), in(15) },   // c1p  K=128
        { in(16), in(17), in(18), in(19), in(20), in(21) },   // c1u  K=256
        { in(22), in(23), in(24), in(25), in(26), in(27) },   // c2p  K=128
        { in(28), in(29), in(30), in(31), in(32), in(33) },   // c2u  K=256
        { in(34), in(35), in(36), in(37), in(38), in(39) },   // post K=128
    };
    _Float16* wt[6] = { WT0, WT1, WT2, WT3, WT4, WT5 };
    const int  kk[6] = { 256, 128, 256, 128, 256, 128 };
    for (int l = 0; l < 6; ++l) {
        P.s[l].g = base[l][0]; P.s[l].b = base[l][1]; P.s[l].m = base[l][2];
        P.s[l].v = base[l][3]; P.s[l].W = base[l][4]; P.s[l].bias = base[l][5];
        P.s[l].WT = wt[l]; P.s[l].bout = pb + l * 128; P.s[l].K = kk[l];
    }
    prep_fat<<<800 + NWG, 256, 0, stream>>>(
        P, in(40), in(41), WTc, pbC, esrc, hist, E, NWG);

    bin_row_scan<<<256, 256, 0, stream>>>(hist, rowsum, NWG);

    // ---- F1: pre + c1p (nf f32 -> xA, y)  ||  bin_scatter (extra blocks) ----
    ffn2_mfma<float, true, true, false><<<ffnGrid + NWG, 256, 0, stream>>>(
        nf, 256, nullptr, WT0, pb + 0*128, WT1, pb + 1*128, xA, y, N,
        esrc, edst, hist, rowsum, bucketed, E, NWG, nullptr, nullptr, nullptr);

    bucket_csr<<<NB, 256, 0, stream>>>(bucketed, rowsum, offs, csr_dst, N);

    // ---- conv1 aggregate ----
    aggregate_kernel<<<(N * 64 + 255) / 256, 256, 0, stream>>>(y, csr_dst, offs, agg, N);

    // ---- F2: c1u + c2p ([xA,agg] -> xB, y) ----
    ffn2_mfma<_Float16, true, false, false><<<ffnGrid, 256, 0, stream>>>(
        xA, 128, agg, WT2, pb + 2*128, WT3, pb + 3*128, xB, y, N,
        nullptr, nullptr, nullptr, nullptr, nullptr, 0, 0, nullptr, nullptr, nullptr);

    // ---- conv2 aggregate ----
    aggregate_kernel<<<(N * 64 + 255) / 256, 256, 0, stream>>>(y, csr_dst, offs, agg, N);

    // ---- F3: c2u + post + fused final linear -> d_out (fp32) ----
    ffn2_mfma<_Float16, false, false, true><<<ffnGrid, 256, 0, stream>>>(
        xB, 128, agg, WT4, pb + 4*128, WT5, pb + 5*128, nullptr, nullptr, N,
        nullptr, nullptr, nullptr, nullptr, nullptr, 0, 0, WTc, pbC, (float*)d_out);
}